// Round 12
// baseline (167.497 us; speedup 1.0000x reference)
//
#include <hip/hip_runtime.h>
#include <hip/hip_bf16.h>

#define NH   16
#define DHD  32
#define SEQ  2048
#define NB   2
#define XROW 1536
#define PP   72   // P-tile pitch (u16), >=64. 144B rows: 16B-aligned, 4-way write conflicts.

typedef unsigned short u16;
typedef __attribute__((ext_vector_type(8))) short bf16x8;
typedef __attribute__((ext_vector_type(4))) float f32x4;

static __device__ __forceinline__ u16 f2b(float f) {
    __hip_bfloat16 h = __float2bfloat16(f);   // RNE (full path; prep only)
    return *(u16*)&h;
}
// exact RNE for non-NaN floats; 3 VALU ops. P=exp(..)>=0 and Q are never NaN.
static __device__ __forceinline__ u16 f2b_fast(float f) {
    unsigned u = __float_as_uint(f);
    u += 0x7FFFu + ((u >> 16) & 1u);
    return (u16)(u >> 16);
}

// ---------- prep: K,E -> bf16, V -> bf16 transposed ----------
__global__ __launch_bounds__(256)
void prep_all(const float* __restrict__ x, const float* __restrict__ E,
              u16* __restrict__ Kb, u16* __restrict__ Vt, u16* __restrict__ Eb) {
    __shared__ float t[64][33];
    int bid = blockIdx.x;
    int tid = threadIdx.x;
    if (bid < 1024) {                 // K -> bf16 [bh][s][d]
        long o = ((long)bid * 256 + tid) * 8;
        int d = (int)(o & 31);
        int s = (int)((o >> 5) & (SEQ - 1));
        int bh = (int)(o >> 16);
        int b = bh >> 4, h = bh & 15;
        const float* src = x + ((long)(b * SEQ + s)) * XROW + 512 + h * 32 + d;
        float4 f0 = *(const float4*)src, f1 = *(const float4*)(src + 4);
        u16 pk[8] = {f2b(f0.x), f2b(f0.y), f2b(f0.z), f2b(f0.w),
                     f2b(f1.x), f2b(f1.y), f2b(f1.z), f2b(f1.w)};
        *(uint4*)(Kb + o) = *(uint4*)pk;
    } else if (bid < 1536) {          // E -> bf16 dense [h][m][d]
        long o = ((long)(bid - 1024) * 256 + tid) * 8;
        const float* src = E + o;
        float4 f0 = *(const float4*)src, f1 = *(const float4*)(src + 4);
        u16 pk[8] = {f2b(f0.x), f2b(f0.y), f2b(f0.z), f2b(f0.w),
                     f2b(f1.x), f2b(f1.y), f2b(f1.z), f2b(f1.w)};
        *(uint4*)(Eb + o) = *(uint4*)pk;
    } else {                          // V -> bf16 transposed [bh][d][s]
        int vb = bid - 1536;
        int bh = vb & 31;
        int s0 = (vb >> 5) << 6;
        int b = bh >> 4, h = bh & 15;
        int sr = tid >> 3, d4 = (tid & 7) * 4;
        const float* base = x + (long)b * SEQ * XROW + 1024 + h * 32;
        float4 f = *(const float4*)(base + (long)(s0 + sr) * XROW + d4);
        t[sr][d4] = f.x; t[sr][d4+1] = f.y; t[sr][d4+2] = f.z; t[sr][d4+3] = f.w;
        f = *(const float4*)(base + (long)(s0 + sr + 32) * XROW + d4);
        t[sr+32][d4] = f.x; t[sr+32][d4+1] = f.y; t[sr+32][d4+2] = f.z; t[sr+32][d4+3] = f.w;
        __syncthreads();
        int d = tid >> 3, sg = (tid & 7) * 8;
        u16 pk[8];
#pragma unroll
        for (int k = 0; k < 8; ++k) pk[k] = f2b(t[sg + k][d]);
        *(uint4*)(Vt + ((long)(bh * 32 + d)) * SEQ + s0 + sg) = *(uint4*)pk;
    }
}

// ---------- MFMA flash attention: paired tiles (p, 127-p), 1 generation ----------
__global__ __launch_bounds__(256, 8)
void attn_mfma(const float* __restrict__ x, const u16* __restrict__ Kb,
               const u16* __restrict__ Vt, const u16* __restrict__ Eb,
               float* __restrict__ out, float* __restrict__ pres) {
    __shared__ u16  pls[4][16 * PP];
    __shared__ float comb[4][16][33];   // cols 0..31 = O, col 32 = l

    int bh = blockIdx.x & 31;
    int pr = blockIdx.x >> 5;           // 0..63
    int b = bh >> 4, h = bh & 15;
    int wv   = threadIdx.x >> 6;
    int lane = threadIdx.x & 63;
    int n16  = lane & 15;
    int quad = lane >> 4;

    const u16* Kbh = Kb + (long)bh * SEQ * 32;
    const u16* Vbh = Vt + (long)bh * 32 * SEQ;
    const u16* Ebh = Eb + (long)h * SEQ * 32;

    bf16x8 ones;
#pragma unroll
    for (int k = 0; k < 8; ++k) ones[k] = (short)0x3F80;   // bf16 1.0

    const f32x4 zero = {0.f,0.f,0.f,0.f};
    const float scale = 0.17677669529663687f;   // rsqrt(32)
    u16* pw = &pls[wv][0];
    int cbase = 15 - quad * 4 + n16;
    int permhi = (lane & 48) << 2;

    for (int half = 0; half < 2; ++half) {
        int gt = half ? (127 - pr) : pr;    // paired tiles: chunk sum ~const (perfect balance)
        int i0 = gt * 16;

        // Q frag from x fp32, scale folded in
        bf16x8 qf;
        {
            const float* qp = x + ((long)(b * SEQ) + i0 + n16) * XROW + h * 32 + quad * 8;
            float4 f0 = *(const float4*)qp, f1 = *(const float4*)(qp + 4);
            u16 pk[8] = {f2b_fast(f0.x*scale), f2b_fast(f0.y*scale),
                         f2b_fast(f0.z*scale), f2b_fast(f0.w*scale),
                         f2b_fast(f1.x*scale), f2b_fast(f1.y*scale),
                         f2b_fast(f1.z*scale), f2b_fast(f1.w*scale)};
            qf = *(bf16x8*)pk;
        }

        f32x4 O0 = {0.f,0.f,0.f,0.f}, O1 = {0.f,0.f,0.f,0.f}, Os = {0.f,0.f,0.f,0.f};

        int nch = (i0 >> 6) + 1;
        for (int ch = wv; ch < nch; ch += 4) {   // split-K across the block's 4 waves
            int j0c = ch << 6;
            int mw0 = 2032 - i0 + j0c;           // E window base (>= 0)

            f32x4 P0, P1;
            float rel0[4];
            {
                int row = mw0 + n16; if (row > SEQ - 1) row = SEQ - 1;
                bf16x8 ef = *(const bf16x8*)(Ebh + (long)row * 32 + quad * 8);
                P0 = __builtin_amdgcn_mfma_f32_16x16x32_bf16(qf, ef, zero, 0, 0, 0);
            }
#pragma unroll
            for (int r = 0; r < 4; ++r) {        // permuted frag-0 values
                int addr = permhi | (((cbase - r) & 15) << 2);
                rel0[r] = __int_as_float(
                    __builtin_amdgcn_ds_bpermute(addr, __float_as_int(P0[r])));
            }
            f32x4 w[4];
#pragma unroll
            for (int s = 0; s < 4; ++s) {
                {
                    int row = mw0 + 16 * (s + 1) + n16; if (row > SEQ - 1) row = SEQ - 1;
                    bf16x8 ef = *(const bf16x8*)(Ebh + (long)row * 32 + quad * 8);
                    P1 = __builtin_amdgcn_mfma_f32_16x16x32_bf16(qf, ef, zero, 0, 0, 0);
                }
                f32x4 C;
                {
                    bf16x8 kf = *(const bf16x8*)(Kbh + (long)(j0c + 16*s + n16) * 32 + quad * 8);
                    C = __builtin_amdgcn_mfma_f32_16x16x32_bf16(qf, kf, zero, 0, 0, 0);
                }
#pragma unroll
                for (int r = 0; r < 4; ++r) {    // skew-select rel; reuse prev permute
                    int c = cbase - r;
                    int addr = permhi | ((c & 15) << 2);
                    float rel1 = __int_as_float(
                        __builtin_amdgcn_ds_bpermute(addr, __float_as_int(P1[r])));
                    float rel = (c < 16) ? rel0[r] : rel1;
                    w[s][r] = C[r] + rel;
                    rel0[r] = rel1;
                }
                P0 = P1;
            }

            if (ch == nch - 1) {                 // causal mask (diagonal chunk only)
                int jb = j0c + n16 - i0;
#pragma unroll
                for (int s = 0; s < 4; ++s)
#pragma unroll
                    for (int r = 0; r < 4; ++r)
                        if (jb + 16 * s > quad * 4 + r) w[s][r] = -1e30f;
            }

#pragma unroll
            for (int s = 0; s < 4; ++s)
#pragma unroll
                for (int r = 0; r < 4; ++r)
                    w[s][r] = __expf(w[s][r]);   // fixed-max softmax; masked -> 0

            // P -> LDS (C-layout), re-read as A-frags (per-wave private, no barrier)
#pragma unroll
            for (int s = 0; s < 4; ++s)
#pragma unroll
                for (int r = 0; r < 4; ++r)
                    pw[(quad * 4 + r) * PP + 16 * s + n16] = f2b_fast(w[s][r]);

            bf16x8 pa0 = *(const bf16x8*)(pw + n16 * PP + quad * 8);
            bf16x8 pa1 = *(const bf16x8*)(pw + n16 * PP + 32 + quad * 8);

            bf16x8 v00 = *(const bf16x8*)(Vbh + (long)n16 * SEQ        + j0c      + quad * 8);
            bf16x8 v01 = *(const bf16x8*)(Vbh + (long)n16 * SEQ        + j0c + 32 + quad * 8);
            bf16x8 v10 = *(const bf16x8*)(Vbh + (long)(16 + n16) * SEQ + j0c      + quad * 8);
            bf16x8 v11 = *(const bf16x8*)(Vbh + (long)(16 + n16) * SEQ + j0c + 32 + quad * 8);

            O0 = __builtin_amdgcn_mfma_f32_16x16x32_bf16(pa0, v00, O0, 0, 0, 0);
            O0 = __builtin_amdgcn_mfma_f32_16x16x32_bf16(pa1, v01, O0, 0, 0, 0);
            O1 = __builtin_amdgcn_mfma_f32_16x16x32_bf16(pa0, v10, O1, 0, 0, 0);
            O1 = __builtin_amdgcn_mfma_f32_16x16x32_bf16(pa1, v11, O1, 0, 0, 0);
            Os = __builtin_amdgcn_mfma_f32_16x16x32_bf16(pa0, ones, Os, 0, 0, 0);
            Os = __builtin_amdgcn_mfma_f32_16x16x32_bf16(pa1, ones, Os, 0, 0, 0);
        }

        if (half) __syncthreads();   // protect comb from half-0 readers

        // per-wave partials -> LDS (fixed-max partials are exactly additive)
#pragma unroll
        for (int r = 0; r < 4; ++r) {
            comb[wv][quad * 4 + r][n16]      = O0[r];
            comb[wv][quad * 4 + r][16 + n16] = O1[r];
            if (n16 == 0) comb[wv][quad * 4 + r][32] = Os[r];
        }
        __syncthreads();

        int row = threadIdx.x >> 4;          // 0..15
        int c2  = (threadIdx.x & 15) * 2;    // 0,2,..,30
        float s0 = 0.f, s1 = 0.f, ls = 0.f;
#pragma unroll
        for (int v = 0; v < 4; ++v) {
            s0 += comb[v][row][c2];
            s1 += comb[v][row][c2 + 1];
            ls += comb[v][row][32];
        }
        float inv = 1.0f / ls;
        float* op = out + ((long)(b * SEQ) + i0 + row) * 512 + h * 32 + c2;
        op[0] = s0 * inv;
        op[1] = s1 * inv;
    }

    // ---- fused present tail: this block's slice of the [B,2,H,S,D] relayout ----
    {
        long o = ((long)blockIdx.x * 256 + threadIdx.x) * 8;   // 2048*256*8 = 4,194,304
#pragma unroll
        for (int t = 0; t < 2; ++t) {
            long oo = o + t * 4;
            int d0 = (int)(oo & 31);
            int s  = (int)((oo >> 5) & (SEQ - 1));
            int hh = (int)((oo >> 16) & (NH - 1));
            int cc = (int)((oo >> 20) & 1);
            int bb = (int)(oo >> 21);
            const float4* in = (const float4*)(x + ((long)(bb * SEQ + s)) * XROW
                                               + (1 + cc) * 512 + hh * 32 + d0);
            *((float4*)(pres + oo)) = in[0];
        }
    }
}

// ---------- fallback path (ws too small): scalar flash + present ----------
__global__ void present_copy(const float* __restrict__ x, float* __restrict__ pres) {
    long o = ((long)blockIdx.x * blockDim.x + threadIdx.x) * 4;
    int d0 = (int)(o & 31);
    int s  = (int)((o >> 5) & (SEQ - 1));
    int h  = (int)((o >> 16) & (NH - 1));
    int c  = (int)((o >> 20) & 1);
    int b  = (int)(o >> 21);
    const float4* in = (const float4*)(x + ((long)(b * SEQ + s)) * XROW
                                       + (1 + c) * 512 + h * 32 + d0);
    *((float4*)(pres + o)) = in[0];
}

__global__ __launch_bounds__(128)
void attn_mono(const float* __restrict__ x, const float* __restrict__ E,
               float* __restrict__ out) {
    __shared__ float kt[64][36];
    __shared__ float vt[64][36];
    __shared__ float et[192][33];
    int bh = blockIdx.x & 31;
    int rt = 15 - (blockIdx.x >> 5);
    int b = bh >> 4, h = bh & 15;
    int tid = threadIdx.x;
    int r0 = rt * 128;
    int i = r0 + tid;
    float q[DHD];
    const float4* q4 = (const float4*)(x + ((long)(b * SEQ + i)) * XROW + h * 32);
#pragma unroll
    for (int t = 0; t < 8; ++t) ((float4*)q)[t] = q4[t];
    float m = -1e30f, l = 0.f;
    float acc[DHD];
#pragma unroll
    for (int d = 0; d < DHD; ++d) acc[d] = 0.f;
    const float* Eh = E + (long)h * SEQ * DHD;
    int ntile = (rt + 1) * 2;
    for (int t0 = 0; t0 < ntile; ++t0) {
        int j0 = t0 * 64;
        {
            int r = tid & 63, isv = tid >> 6;
            const float4* s4 = (const float4*)(x + ((long)(b * SEQ + j0 + r)) * XROW
                                               + (1 + isv) * 512 + h * 32);
            float4 tmp[8];
#pragma unroll
            for (int t = 0; t < 8; ++t) tmp[t] = s4[t];
            float* dst = isv ? &vt[r][0] : &kt[r][0];
#pragma unroll
            for (int t = 0; t < 8; ++t) ((float4*)dst)[t] = tmp[t];
        }
        {
            int eb0 = (SEQ - 1) - (r0 + 127) + j0;
#pragma unroll
            for (int p = 0; p < 12; ++p) {
                int idx = p * 128 + tid;
                int r = idx >> 3, qq = idx & 7;
                int gr = eb0 + r; if (gr > SEQ - 1) gr = SEQ - 1;
                float4 gg = *(const float4*)(Eh + (long)gr * DHD + qq * 4);
                et[r][qq*4+0] = gg.x; et[r][qq*4+1] = gg.y;
                et[r][qq*4+2] = gg.z; et[r][qq*4+3] = gg.w;
            }
        }
        __syncthreads();
        int jend = i - j0 + 1; if (jend > 64) jend = 64;
        int er0 = 127 - tid;
        for (int jj = 0; jj < jend; ++jj) {
            const float* ep = &et[er0 + jj][0];
            float dk = 0.f, de = 0.f;
#pragma unroll
            for (int d = 0; d < DHD; ++d) {
                dk = __builtin_fmaf(q[d], kt[jj][d], dk);
                de = __builtin_fmaf(q[d], ep[d], de);
            }
            float sc = (dk + de) * 0.17677669529663687f;
            if (sc > m) {
                float r = __expf(m - sc);
                l *= r;
#pragma unroll
                for (int d = 0; d < DHD; ++d) acc[d] *= r;
                m = sc;
            }
            float p = __expf(sc - m);
            l += p;
#pragma unroll
            for (int d = 0; d < DHD; ++d)
                acc[d] = __builtin_fmaf(p, vt[jj][d], acc[d]);
        }
        __syncthreads();
    }
    float inv = 1.0f / l;
    float* op = out + ((long)(b * SEQ + i)) * 512 + h * 32;
#pragma unroll
    for (int t = 0; t < 8; ++t) {
        float4 w;
        w.x = acc[t*4+0]*inv; w.y = acc[t*4+1]*inv;
        w.z = acc[t*4+2]*inv; w.w = acc[t*4+3]*inv;
        ((float4*)op)[t] = w;
    }
}

extern "C" void kernel_launch(void* const* d_in, const int* in_sizes, int n_in,
                              void* d_out, int out_size, void* d_ws, size_t ws_size,
                              hipStream_t stream) {
    const float* x = (const float*)d_in[0];
    const float* E = (const float*)d_in[1];
    if (n_in >= 2 && in_sizes[0] == 1048576) { const float* t = x; x = E; E = t; }
    float* a    = (float*)d_out;
    float* pres = a + (long)NB * SEQ * NH * DHD;

    const long KN = (long)NB * NH * SEQ * 32;            // 2,097,152
    const long EN = (long)NH * SEQ * 32;                 // 1,048,576
    const size_t WS_NEED = (size_t)(2 * KN + EN) * sizeof(u16);   // ~10.5 MB
    if (ws_size >= WS_NEED) {
        u16* Kb = (u16*)d_ws;
        u16* Vt = Kb + KN;
        u16* Eb = Vt + KN;
        prep_all<<<dim3(2560), dim3(256), 0, stream>>>(x, E, Kb, Vt, Eb);
        attn_mfma<<<dim3(2048), dim3(256), 0, stream>>>(x, Kb, Vt, Eb, a, pres);
    } else {
        attn_mono<<<dim3(512), dim3(128), 0, stream>>>(x, E, a);
        present_copy<<<dim3(4096), dim3(256), 0, stream>>>(x, pres);
    }
}